// Round 5
// baseline (1617.578 us; speedup 1.0000x reference)
//
#include <hip/hip_runtime.h>
#include <hip/hip_bf16.h>

// RetinaNet head on MI355X. R5: deep-pipelined phase-interleaved implicit-GEMM
// (T2+T3+T4+T5): BM=256 x BN=128, 4 waves 2x2 (wave tile 128x64), BK=32,
// ring-3 LDS, stage 2 K-tiles ahead, vmcnt(6) per K-tile, 2 sub-phases of
// 16 MFMA each, XOR slot-swizzle both sides.

typedef float  f32x4 __attribute__((ext_vector_type(4)));
typedef int    i32x4 __attribute__((ext_vector_type(4)));
typedef __bf16 bfrag __attribute__((ext_vector_type(8)));
typedef __bf16 bf4   __attribute__((ext_vector_type(4)));

struct LevelD {
  int H, W, logW, logHW, P, HW, act_off, aoff, blk_start, pos_start;
};
struct Desc  { LevelD lv[6]; };
struct FPtrs { const float* f[6]; };

#define ACT_ELEMS  24735744
#define WREG_OFF   0
#define WCLS_OFF   2359296
#define WREGO_OFF  4718592
#define WCLSO_OFF  4773888
#define ACT0_OFF   4898304
#define ACT1_OFF   29634048
#define WS_ELEMS   54369792ull
#define TOTAL_ANCH 65520
#define CLS_BASE   2096640

__device__ __forceinline__ void glds16(const __bf16* g, __bf16* l) {
  __builtin_amdgcn_global_load_lds(
      (const __attribute__((address_space(1))) void*)g,
      (__attribute__((address_space(3))) void*)l, 16, 0, 0);
}
__device__ __forceinline__ void memfence_compiler() {
  asm volatile("" ::: "memory");
}

// ---- weight prep: [CO][256ci][3][3] f32 -> [CO][t=9][256ci] bf16 ----
__global__ __launch_bounds__(256) void prep_k(const float* __restrict__ w,
                                              __bf16* __restrict__ o, int total)
{
  for (int i = blockIdx.x * 256 + threadIdx.x; i < total; i += gridDim.x * 256) {
    int co = i / 2304;
    int r  = i - co * 2304;
    int t  = r >> 8;
    int ci = r & 255;
    o[i] = (__bf16)w[((co << 8) + ci) * 9 + t];
  }
}

// ---- NCHW f32 feat -> padded NHWC bf16 (interior only; halos pre-zeroed) ----
__global__ __launch_bounds__(256) void convert_k(FPtrs fp, __bf16* __restrict__ act, Desc d)
{
  __shared__ __bf16 T[16 * 264];
  int b  = blockIdx.x;
  int p0 = b << 4;
  int li = 0;
  #pragma unroll
  for (int i = 1; i < 6; ++i) li = (p0 >= d.lv[i].pos_start) ? i : li;
  LevelD L = d.lv[li];
  int lp  = b * 16 - L.pos_start;
  int tid = threadIdx.x;
  int pl = tid & 15;
  int p  = lp + pl;
  int n  = p >> L.logHW;
  int y  = (p >> L.logW) & (L.H - 1);
  int x  = p & (L.W - 1);
  const float* src = fp.f[li];
  size_t base = (size_t)n * ((size_t)L.HW << 8) + (size_t)y * L.W + x;
  int c0 = tid >> 4;
  #pragma unroll
  for (int it = 0; it < 16; ++it) {
    int c = c0 + (it << 4);
    T[pl * 264 + c] = (__bf16)src[base + (size_t)c * L.HW];
  }
  __syncthreads();
  int p2 = tid >> 4;
  int cc = (tid & 15) << 4;
  int pg = lp + p2;
  int n2 = pg >> L.logHW;
  int y2 = (pg >> L.logW) & (L.H - 1);
  int x2 = pg & (L.W - 1);
  __bf16* dst = act + L.act_off +
      ((size_t)((n2 * (L.H + 2) + y2 + 1) * (L.W + 2) + x2 + 1) << 8) + cc;
  i32x4 v0 = *(const i32x4*)&T[p2 * 264 + cc];
  i32x4 v1 = *(const i32x4*)&T[p2 * 264 + cc + 8];
  *(i32x4*)dst       = v0;
  *(i32x4*)(dst + 8) = v1;
}

// swizzle: f(row) on 16B slots within a 64B (32-elem) row chunk
__device__ __forceinline__ int fsw(int row) { return (row ^ (row >> 2)) & 3; }

// ---- mid conv: 256->256, +bias, ReLU. BM=256 co, BN=128 pos ----
__global__ __launch_bounds__(256, 2)
void conv_mid_k(const __bf16* __restrict__ inb, __bf16* __restrict__ outb,
                const __bf16* __restrict__ wT, const float* __restrict__ bias,
                Desc d)
{
  __shared__ __bf16 Asm[3 * 8192];   // 3 bufs x [256 rows][32 k], 64B rows
  __shared__ __bf16 Bsm[3 * 4096];   // 3 bufs x [128 rows][32 k]
  int b  = blockIdx.x;
  int li = 0;
  #pragma unroll
  for (int i = 1; i < 6; ++i) li = (b >= d.lv[i].blk_start) ? i : li;
  LevelD L = d.lv[li];
  int p0 = (b - L.blk_start) << 7;
  int tid  = threadIdx.x;
  int lane = tid & 63;
  int wv   = tid >> 6;
  int wm = wv >> 1, wn = wv & 1;
  int fr = lane & 15, fg = lane >> 4;
  int Wp = L.W + 2;

  // ---- staging decode: per glds round, wave covers 16 rows x 4 slots ----
  int srow = lane >> 2;         // 0..15 within wave's 16-row group
  int slot = lane & 3;          // phys 16B slot

  const __bf16* gA[4];          // A rounds i: rows i*64 + wv*16 + srow
  #pragma unroll
  for (int i = 0; i < 4; ++i) {
    int row = (i << 6) + (wv << 4) + srow;
    gA[i] = wT + row * 2304 + ((slot ^ fsw(row)) << 3);
  }
  const __bf16* gB[2];          // B rounds j: rows j*64 + wv*16 + srow
  #pragma unroll
  for (int j = 0; j < 2; ++j) {
    int row = (j << 6) + (wv << 4) + srow;
    int p  = p0 + row;
    int pc = (p < L.P) ? p : 0;
    int n = pc >> L.logHW, y = (pc >> L.logW) & (L.H - 1), x = pc & (L.W - 1);
    gB[j] = inb + L.act_off + (((n * (L.H + 2) + y) * Wp + x) << 8)
            + ((slot ^ fsw(row)) << 3);
  }
  int dA = (wv << 4) << 5;      // wave dest base elems: (wv*16)*32
  int dB = dA;

  // ---- fragment read byte offsets (swizzled) ----
  int offA[8], offB[4];
  #pragma unroll
  for (int mf = 0; mf < 8; ++mf) {
    int row = (wm << 7) + (mf << 4) + fr;
    offA[mf] = (row << 6) + ((fg ^ fsw(row)) << 4);
  }
  #pragma unroll
  for (int nf = 0; nf < 4; ++nf) {
    int row = (wn << 6) + (nf << 4) + fr;
    offB[nf] = (row << 6) + ((fg ^ fsw(row)) << 4);
  }

  // stage helpers: K-tile kt -> A elem-offset kt*32; B needs tap decode
  auto stageA012 = [&](int kt, int buf) {
    int ka = kt << 5;
    __bf16* base = Asm + buf * 8192;
    glds16(gA[0] + ka, base + dA);
    glds16(gA[1] + ka, base + 2048 + dA);
    glds16(gA[2] + ka, base + 4096 + dA);
  };
  auto stageA3B = [&](int kt, int buf) {
    int ka = kt << 5;
    int t  = kt >> 3;
    int ky = (t >= 6) ? 2 : (t >= 3 ? 1 : 0);
    int kx = t - ky * 3;
    int kb = ((ky * Wp + kx) << 8) + ((kt & 7) << 5);
    glds16(gA[3] + ka, Asm + buf * 8192 + 6144 + dA);
    __bf16* bb = Bsm + buf * 4096;
    glds16(gB[0] + kb, bb + dB);
    glds16(gB[1] + kb, bb + 2048 + dB);
  };

  f32x4 acc[8][4] = {};
  bfrag bfv[4];

  auto readB = [&](int buf) {
    const char* Bp = (const char*)(Bsm + buf * 4096);
    #pragma unroll
    for (int nf = 0; nf < 4; ++nf) bfv[nf] = *(const bfrag*)(Bp + offB[nf]);
  };
  auto half = [&](int buf, int m0) {
    const char* Ap = (const char*)(Asm + buf * 8192);
    bfrag af[4];
    #pragma unroll
    for (int m = 0; m < 4; ++m) af[m] = *(const bfrag*)(Ap + offA[m0 + m]);
    asm volatile("s_waitcnt lgkmcnt(0)" ::: "memory");
    __builtin_amdgcn_sched_barrier(0);
    __builtin_amdgcn_s_setprio(1);
    #pragma unroll
    for (int m = 0; m < 4; ++m)
      #pragma unroll
      for (int nf = 0; nf < 4; ++nf)
        acc[m0 + m][nf] = __builtin_amdgcn_mfma_f32_16x16x32_bf16(
            af[m], bfv[nf], acc[m0 + m][nf], 0, 0, 0);
    __builtin_amdgcn_s_setprio(0);
  };

  // prologue: stage kt0, kt1
  stageA012(0, 0); stageA3B(0, 0);
  stageA012(1, 1); stageA3B(1, 1);

  int cur = 0;
  #pragma unroll 1
  for (int kt = 0; kt < 71; ++kt) {
    int s2 = cur + 2; if (s2 >= 3) s2 -= 3;       // (kt+2)%3
    asm volatile("s_waitcnt vmcnt(6)" ::: "memory");
    __builtin_amdgcn_s_barrier();
    memfence_compiler();
    // phase 0: B frags + A lower half, stage first 3 loads of kt+2
    readB(cur);
    if (kt < 70) stageA012(kt + 2, s2);
    half(cur, 0);
    __builtin_amdgcn_s_barrier();
    memfence_compiler();
    // phase 1: A upper half, stage last 3 loads of kt+2
    if (kt < 70) stageA3B(kt + 2, s2);
    half(cur, 4);
    ++cur; if (cur == 3) cur = 0;
  }
  // final K-tile (71): full drain
  asm volatile("s_waitcnt vmcnt(0)" ::: "memory");
  __builtin_amdgcn_s_barrier();
  memfence_compiler();
  readB(cur);
  half(cur, 0);
  half(cur, 4);

  // epilogue: bias + relu -> bf16 NHWC interior
  #pragma unroll
  for (int nf = 0; nf < 4; ++nf) {
    int pp = p0 + (wn << 6) + (nf << 4) + fr;
    if (pp >= L.P) continue;
    int n2 = pp >> L.logHW;
    int y2 = (pp >> L.logW) & (L.H - 1);
    int x2 = pp & (L.W - 1);
    __bf16* ob = outb + L.act_off + (((n2 * (L.H + 2) + y2 + 1) * Wp + x2 + 1) << 8);
    #pragma unroll
    for (int mf = 0; mf < 8; ++mf) {
      int cob = (wm << 7) + (mf << 4) + (fg << 2);
      f32x4 bb = *(const f32x4*)(bias + cob);
      f32x4 v  = acc[mf][nf];
      bf4 ov;
      #pragma unroll
      for (int j = 0; j < 4; ++j) ov[j] = (__bf16)fmaxf(v[j] + bb[j], 0.0f);
      *(bf4*)(ob + cob) = ov;
    }
  }
}

// ---- out conv: 256->Cout (24/54), BM=64, +bias, scatter f32 to d_out ----
__global__ __launch_bounds__(256, 2)
void conv_out_k(const __bf16* __restrict__ inb, const __bf16* __restrict__ wT,
                const float* __restrict__ biasO, float* __restrict__ dout,
                Desc d, int Cout, int isCls)
{
  __shared__ __bf16 Asm[3 * 2048];   // 3 x [64][32]
  __shared__ __bf16 Bsm[3 * 4096];   // 3 x [128][32]
  int b  = blockIdx.x;
  int li = 0;
  #pragma unroll
  for (int i = 1; i < 6; ++i) li = (b >= d.lv[i].blk_start) ? i : li;
  LevelD L = d.lv[li];
  int p0 = (b - L.blk_start) << 7;
  int tid  = threadIdx.x;
  int lane = tid & 63;
  int wv   = tid >> 6;            // wave = pos quarter (1x4)
  int fr = lane & 15, fg = lane >> 4;
  int Wp = L.W + 2;
  int nmf = (Cout + 15) >> 4;     // 2 (reg) or 4 (cls)

  int srow = lane >> 2;
  int slot = lane & 3;

  const __bf16* gA0;
  {
    int row = (wv << 4) + srow;               // 0..63
    int co  = (row < Cout) ? row : 0;
    gA0 = wT + co * 2304 + ((slot ^ fsw(row)) << 3);
  }
  const __bf16* gB[2];
  #pragma unroll
  for (int j = 0; j < 2; ++j) {
    int row = (j << 6) + (wv << 4) + srow;
    int p  = p0 + row;
    int pc = (p < L.P) ? p : 0;
    int n = pc >> L.logHW, y = (pc >> L.logW) & (L.H - 1), x = pc & (L.W - 1);
    gB[j] = inb + L.act_off + (((n * (L.H + 2) + y) * Wp + x) << 8)
            + ((slot ^ fsw(row)) << 3);
  }
  int dW = (wv << 4) << 5;

  int offA[4], offB[2];
  #pragma unroll
  for (int mf = 0; mf < 4; ++mf) {
    int row = (mf << 4) + fr;
    offA[mf] = (row << 6) + ((fg ^ fsw(row)) << 4);
  }
  #pragma unroll
  for (int nf = 0; nf < 2; ++nf) {
    int row = (wv << 5) + (nf << 4) + fr;
    offB[nf] = (row << 6) + ((fg ^ fsw(row)) << 4);
  }

  auto stage = [&](int kt, int buf) {
    int ka = kt << 5;
    int t  = kt >> 3;
    int ky = (t >= 6) ? 2 : (t >= 3 ? 1 : 0);
    int kx = t - ky * 3;
    int kb = ((ky * Wp + kx) << 8) + ((kt & 7) << 5);
    glds16(gA0 + ka, Asm + buf * 2048 + dW);
    __bf16* bb = Bsm + buf * 4096;
    glds16(gB[0] + kb, bb + dW);
    glds16(gB[1] + kb, bb + 2048 + dW);
  };

  f32x4 acc[4][2] = {};

  auto compute = [&](int buf) {
    const char* Ap = (const char*)(Asm + buf * 2048);
    const char* Bp = (const char*)(Bsm + buf * 4096);
    bfrag af[4], bfv[2];
    #pragma unroll
    for (int mf = 0; mf < 4; ++mf)
      if (mf < nmf) af[mf] = *(const bfrag*)(Ap + offA[mf]);
    #pragma unroll
    for (int nf = 0; nf < 2; ++nf) bfv[nf] = *(const bfrag*)(Bp + offB[nf]);
    asm volatile("s_waitcnt lgkmcnt(0)" ::: "memory");
    __builtin_amdgcn_sched_barrier(0);
    __builtin_amdgcn_s_setprio(1);
    #pragma unroll
    for (int mf = 0; mf < 4; ++mf)
      if (mf < nmf)
        #pragma unroll
        for (int nf = 0; nf < 2; ++nf)
          acc[mf][nf] = __builtin_amdgcn_mfma_f32_16x16x32_bf16(
              af[mf], bfv[nf], acc[mf][nf], 0, 0, 0);
    __builtin_amdgcn_s_setprio(0);
  };

  stage(0, 0);
  stage(1, 1);
  int cur = 0;
  #pragma unroll 1
  for (int kt = 0; kt < 71; ++kt) {
    int s2 = cur + 2; if (s2 >= 3) s2 -= 3;
    asm volatile("s_waitcnt vmcnt(3)" ::: "memory");
    __builtin_amdgcn_s_barrier();
    memfence_compiler();
    if (kt < 70) stage(kt + 2, s2);
    compute(cur);
    ++cur; if (cur == 3) cur = 0;
  }
  asm volatile("s_waitcnt vmcnt(0)" ::: "memory");
  __builtin_amdgcn_s_barrier();
  memfence_compiler();
  compute(cur);

  // scatter epilogue
  #pragma unroll
  for (int nf = 0; nf < 2; ++nf) {
    int pp = p0 + (wv << 5) + (nf << 4) + fr;
    if (pp >= L.P) continue;
    int n2 = pp >> L.logHW;
    int y2 = (pp >> L.logW) & (L.H - 1);
    int x2 = pp & (L.W - 1);
    int sp_off = L.aoff + y2 * L.W + x2;
    #pragma unroll
    for (int mf = 0; mf < 4; ++mf) {
      if (mf < nmf) {
        #pragma unroll
        for (int j = 0; j < 4; ++j) {
          int co = (mf << 4) + (fg << 2) + j;
          if (co < Cout) {
            float val = acc[mf][nf][j] + biasO[co];
            int g   = co / 6;
            int box = co - g * 6;
            size_t idx;
            if (isCls) idx = (size_t)CLS_BASE + ((size_t)n2 * 9 + g) * TOTAL_ANCH
                             + sp_off + box * L.HW;
            else       idx = ((size_t)n2 * 4 + g) * TOTAL_ANCH + sp_off + box * L.HW;
            dout[idx] = val;
          }
        }
      }
    }
  }
}

extern "C" void kernel_launch(void* const* d_in, const int* in_sizes, int n_in,
                              void* d_out, int out_size, void* d_ws, size_t ws_size,
                              hipStream_t stream) {
  if (ws_size < WS_ELEMS * 2) return;  // fail loud: output stays poisoned

  static const int kH[6]      = {32, 16, 8, 4, 2, 1};
  static const int kW[6]      = {256, 128, 64, 32, 16, 8};
  static const int kLogW[6]   = {8, 7, 6, 5, 4, 3};
  static const int kLogHW[6]  = {13, 11, 9, 7, 5, 3};
  static const int kActOff[6] = {0, 17965056, 22757376, 24109056, 24526848, 24674304};
  static const int kAoff[6]   = {0, 49152, 61440, 64512, 65280, 65472};
  static const int kBlk[6]    = {0, 512, 640, 672, 680, 682};
  static const int kPosSt[6]  = {0, 65536, 81920, 86016, 87040, 87296};

  FPtrs fp;
  for (int i = 0; i < 6; ++i) fp.f[i] = (const float*)d_in[i];
  const float* reg_w  = (const float*)d_in[6];
  const float* reg_b  = (const float*)d_in[7];
  const float* reg_wo = (const float*)d_in[8];
  const float* reg_bo = (const float*)d_in[9];
  const float* cls_w  = (const float*)d_in[10];
  const float* cls_b  = (const float*)d_in[11];
  const float* cls_wo = (const float*)d_in[12];
  const float* cls_bo = (const float*)d_in[13];
  __bf16* ws = (__bf16*)d_ws;

  Desc dd;
  for (int i = 0; i < 6; ++i) {
    LevelD L;
    L.H = kH[i]; L.W = kW[i]; L.logW = kLogW[i]; L.logHW = kLogHW[i];
    L.HW = kH[i] * kW[i]; L.P = 8 * L.HW;
    L.act_off = kActOff[i]; L.aoff = kAoff[i];
    L.blk_start = kBlk[i]; L.pos_start = kPosSt[i];
    dd.lv[i] = L;
  }

  // zero both activation buffers (halos must be zero)
  hipMemsetAsync((char*)d_ws + (size_t)ACT0_OFF * 2, 0,
                 (size_t)ACT_ELEMS * 2 * 2, stream);

  prep_k<<<256, 256, 0, stream>>>(reg_w,  ws + WREG_OFF,  1024 * 2304);
  prep_k<<<256, 256, 0, stream>>>(cls_w,  ws + WCLS_OFF,  1024 * 2304);
  prep_k<<<64,  256, 0, stream>>>(reg_wo, ws + WREGO_OFF, 24 * 2304);
  prep_k<<<64,  256, 0, stream>>>(cls_wo, ws + WCLSO_OFF, 54 * 2304);

  for (int head = 0; head < 2; ++head) {
    convert_k<<<5460, 256, 0, stream>>>(fp, ws + ACT0_OFF, dd);
    const __bf16* wT = ws + (head ? WCLS_OFF : WREG_OFF);
    const float*  bb = head ? cls_b : reg_b;
    conv_mid_k<<<683, 256, 0, stream>>>(ws + ACT0_OFF, ws + ACT1_OFF, wT + 0 * 589824, bb + 0,   dd);
    conv_mid_k<<<683, 256, 0, stream>>>(ws + ACT1_OFF, ws + ACT0_OFF, wT + 1 * 589824, bb + 256, dd);
    conv_mid_k<<<683, 256, 0, stream>>>(ws + ACT0_OFF, ws + ACT1_OFF, wT + 2 * 589824, bb + 512, dd);
    conv_mid_k<<<683, 256, 0, stream>>>(ws + ACT1_OFF, ws + ACT0_OFF, wT + 3 * 589824, bb + 768, dd);
    conv_out_k<<<683, 256, 0, stream>>>(ws + ACT0_OFF,
        ws + (head ? WCLSO_OFF : WREGO_OFF), head ? cls_bo : reg_bo,
        (float*)d_out, dd, head ? 54 : 24, head);
  }
}

// Round 7
// 1437.296 us; speedup vs baseline: 1.1254x; 1.1254x over previous
//
#include <hip/hip_runtime.h>
#include <hip/hip_bf16.h>

// RetinaNet head on MI355X. R7: m97-proven geometry — 128x128 tile, BK=32,
// 4 waves (2x2, wave tile 64x64, acc 64 regs -> 3 waves/SIMD), dbuf 32KB LDS,
// 1 barrier/K-step (stage-before-compute), grid 1366 (89% packing),
// global_load_lds(16B) + XOR slot-swizzle (source+read, linear LDS dest).
// R7 fix vs R6: conv_out fragment reads are ELEMENT-indexed (R6 mixed
// elem-computed offsets with byte-based pointer arithmetic -> wrong rows).

typedef float  f32x4 __attribute__((ext_vector_type(4)));
typedef int    i32x4 __attribute__((ext_vector_type(4)));
typedef __bf16 bfrag __attribute__((ext_vector_type(8)));
typedef __bf16 bf4   __attribute__((ext_vector_type(4)));

struct LevelD {
  int H, W, logW, logHW, P, HW, act_off, aoff, blk_start, pos_start;
};
struct Desc  { LevelD lv[6]; };
struct FPtrs { const float* f[6]; };

#define ACT_ELEMS  24735744
#define WREG_OFF   0
#define WCLS_OFF   2359296
#define WREGO_OFF  4718592
#define WCLSO_OFF  4773888
#define ACT0_OFF   4898304
#define ACT1_OFF   29634048
#define WS_ELEMS   54369792ull
#define TOTAL_ANCH 65520
#define CLS_BASE   2096640

__device__ __forceinline__ void glds16(const __bf16* g, __bf16* l) {
  __builtin_amdgcn_global_load_lds(
      (const __attribute__((address_space(1))) void*)g,
      (__attribute__((address_space(3))) void*)l, 16, 0, 0);
}

// ---- weight prep: [CO][256ci][3][3] f32 -> [CO][t=9][256ci] bf16 ----
__global__ __launch_bounds__(256) void prep_k(const float* __restrict__ w,
                                              __bf16* __restrict__ o, int total)
{
  for (int i = blockIdx.x * 256 + threadIdx.x; i < total; i += gridDim.x * 256) {
    int co = i / 2304;
    int r  = i - co * 2304;
    int t  = r >> 8;
    int ci = r & 255;
    o[i] = (__bf16)w[((co << 8) + ci) * 9 + t];
  }
}

// ---- NCHW f32 feat -> padded NHWC bf16 (interior only; halos pre-zeroed) ----
__global__ __launch_bounds__(256) void convert_k(FPtrs fp, __bf16* __restrict__ act, Desc d)
{
  __shared__ __bf16 T[16 * 264];
  int b  = blockIdx.x;
  int p0 = b << 4;
  int li = 0;
  #pragma unroll
  for (int i = 1; i < 6; ++i) li = (p0 >= d.lv[i].pos_start) ? i : li;
  LevelD L = d.lv[li];
  int lp  = b * 16 - L.pos_start;
  int tid = threadIdx.x;
  int pl = tid & 15;
  int p  = lp + pl;
  int n  = p >> L.logHW;
  int y  = (p >> L.logW) & (L.H - 1);
  int x  = p & (L.W - 1);
  const float* src = fp.f[li];
  size_t base = (size_t)n * ((size_t)L.HW << 8) + (size_t)y * L.W + x;
  int c0 = tid >> 4;
  #pragma unroll
  for (int it = 0; it < 16; ++it) {
    int c = c0 + (it << 4);
    T[pl * 264 + c] = (__bf16)src[base + (size_t)c * L.HW];
  }
  __syncthreads();
  int p2 = tid >> 4;
  int cc = (tid & 15) << 4;
  int pg = lp + p2;
  int n2 = pg >> L.logHW;
  int y2 = (pg >> L.logW) & (L.H - 1);
  int x2 = pg & (L.W - 1);
  __bf16* dst = act + L.act_off +
      ((size_t)((n2 * (L.H + 2) + y2 + 1) * (L.W + 2) + x2 + 1) << 8) + cc;
  i32x4 v0 = *(const i32x4*)&T[p2 * 264 + cc];
  i32x4 v1 = *(const i32x4*)&T[p2 * 264 + cc + 8];
  *(i32x4*)dst       = v0;
  *(i32x4*)(dst + 8) = v1;
}

// ---- mid conv: 256->256, +bias, ReLU ----
// 128x128 tile, BK=32, 4 waves (2x2), dbuf LDS, 1 barrier/K-step.
__global__ __launch_bounds__(256, 3)
void conv_mid_k(const __bf16* __restrict__ inb, __bf16* __restrict__ outb,
                const __bf16* __restrict__ wT, const float* __restrict__ bias,
                Desc d)
{
  __shared__ __bf16 Al[2][128 * 32];   // linear [co][ci32], 64B rows
  __shared__ __bf16 Bl[2][128 * 32];   // linear [pos][ci32]
  int b  = blockIdx.x;
  int li = 0;
  #pragma unroll
  for (int i = 1; i < 6; ++i) li = (b >= d.lv[i].blk_start) ? i : li;
  LevelD L  = d.lv[li];
  int local = b - L.blk_start;
  int mt = local & 1;
  int nt = local >> 1;
  int m0 = mt << 7;
  int p0 = nt << 7;
  int tid  = threadIdx.x;
  int lane = tid & 63;
  int wv   = tid >> 6;
  int wm = wv >> 1, wn = wv & 1;
  int fr = lane & 15, fg = lane >> 4;
  int Wp = L.W + 2;

  // staging decode: wave wv covers rows wv*16 + r*64 (r=0,1), lane -> (rsub, slot)
  int rsub = lane >> 2;
  int slot = lane & 3;
  int sw   = slot ^ ((rsub >> 1) & 3);          // XOR slot-swizzle (source side)

  const __bf16* gA[2];
  const __bf16* gB[2];
  int ldsA[2];
  #pragma unroll
  for (int r = 0; r < 2; ++r) {
    int row = (r << 6) + (wv << 4) + rsub;
    gA[r] = wT + (m0 + row) * 2304 + (sw << 3);
    int p  = p0 + row;
    int pc = (p < L.P) ? p : 0;
    int n  = pc >> L.logHW;
    int y  = (pc >> L.logW) & (L.H - 1);
    int x  = pc & (L.W - 1);
    gB[r] = inb + L.act_off + (((n * (L.H + 2) + y) * Wp + x) << 8) + (sw << 3);
    ldsA[r] = ((r << 6) + (wv << 4)) << 5;      // row*32 elems, wave base
  }

  // fragment read offsets (swizzled column), ELEMENT units
  int csw = ((fg ^ ((fr >> 1) & 3)) << 3);
  int offA[4], offB[4];
  #pragma unroll
  for (int f = 0; f < 4; ++f) {
    offA[f] = (((wm << 6) + (f << 4) + fr) << 5) + csw;
    offB[f] = (((wn << 6) + (f << 4) + fr) << 5) + csw;
  }

  auto stage = [&](int k, int bb) {
    int t  = k >> 3;
    int c0 = (k & 7) << 5;
    int ky = (t >= 6) ? 2 : (t >= 3 ? 1 : 0);
    int kx = t - ky * 3;
    int koffA = (t << 8) + c0;
    int koffB = ((ky * Wp + kx) << 8) + c0;
    glds16(gA[0] + koffA, &Al[bb][ldsA[0]]);
    glds16(gA[1] + koffA, &Al[bb][ldsA[1]]);
    glds16(gB[0] + koffB, &Bl[bb][ldsA[0]]);
    glds16(gB[1] + koffB, &Bl[bb][ldsA[1]]);
  };

  f32x4 acc[4][4] = {};

  stage(0, 0);
  #pragma unroll 1
  for (int k = 0; k < 72; ++k) {
    int cur = k & 1;
    __syncthreads();                 // stage(k) landed (flew during compute(k-1))
    if (k < 71) stage(k + 1, cur ^ 1);
    bfrag af[4], bfv[4];
    #pragma unroll
    for (int mf = 0; mf < 4; ++mf) af[mf]  = *(const bfrag*)&Al[cur][offA[mf]];
    #pragma unroll
    for (int nf = 0; nf < 4; ++nf) bfv[nf] = *(const bfrag*)&Bl[cur][offB[nf]];
    #pragma unroll
    for (int mf = 0; mf < 4; ++mf)
      #pragma unroll
      for (int nf = 0; nf < 4; ++nf)
        acc[mf][nf] = __builtin_amdgcn_mfma_f32_16x16x32_bf16(af[mf], bfv[nf],
                                                              acc[mf][nf], 0, 0, 0);
  }

  // epilogue: bias + relu -> bf16 NHWC interior
  #pragma unroll
  for (int nf = 0; nf < 4; ++nf) {
    int pp = p0 + (wn << 6) + (nf << 4) + fr;
    if (pp >= L.P) continue;
    int n2 = pp >> L.logHW;
    int y2 = (pp >> L.logW) & (L.H - 1);
    int x2 = pp & (L.W - 1);
    __bf16* ob = outb + L.act_off + (((n2 * (L.H + 2) + y2 + 1) * Wp + x2 + 1) << 8);
    #pragma unroll
    for (int mf = 0; mf < 4; ++mf) {
      int cob = m0 + (wm << 6) + (mf << 4) + (fg << 2);
      f32x4 bb = *(const f32x4*)(bias + cob);
      f32x4 v  = acc[mf][nf];
      bf4 ov;
      #pragma unroll
      for (int j = 0; j < 4; ++j) ov[j] = (__bf16)fmaxf(v[j] + bb[j], 0.0f);
      *(bf4*)(ob + cob) = ov;
    }
  }
}

// ---- out conv: 256->Cout (24 reg / 54 cls), +bias, scatter f32 to d_out ----
// BM=Cout (<=64), BN=128; 4 waves = pos quarters, wave tile Cout x 32.
__global__ __launch_bounds__(256, 3)
void conv_out_k(const __bf16* __restrict__ inb, const __bf16* __restrict__ wT,
                const float* __restrict__ biasO, float* __restrict__ dout,
                Desc d, int Cout, int isCls)
{
  __shared__ __bf16 Asm[2][64 * 32];
  __shared__ __bf16 Bsm[2][128 * 32];
  int b  = blockIdx.x;
  int li = 0;
  #pragma unroll
  for (int i = 1; i < 6; ++i) li = (b >= d.lv[i].blk_start) ? i : li;
  LevelD L = d.lv[li];
  int p0 = (b - L.blk_start) << 7;
  int tid  = threadIdx.x;
  int lane = tid & 63;
  int wv   = tid >> 6;            // wave = pos quarter
  int fr = lane & 15, fg = lane >> 4;
  int Wp = L.W + 2;
  int nmf = (Cout + 15) >> 4;     // 2 (reg) or 4 (cls)

  int rsub = lane >> 2;
  int slot = lane & 3;
  int sw   = slot ^ ((rsub >> 1) & 3);

  const __bf16* gA0;
  {
    int row = (wv << 4) + rsub;               // 0..63
    int co  = (row < Cout) ? row : 0;
    gA0 = wT + co * 2304 + (sw << 3);
  }
  const __bf16* gB[2];
  #pragma unroll
  for (int j = 0; j < 2; ++j) {
    int row = (j << 6) + (wv << 4) + rsub;
    int p  = p0 + row;
    int pc = (p < L.P) ? p : 0;
    int n = pc >> L.logHW, y = (pc >> L.logW) & (L.H - 1), x = pc & (L.W - 1);
    gB[j] = inb + L.act_off + (((n * (L.H + 2) + y) * Wp + x) << 8) + (sw << 3);
  }
  int dW = (wv << 4) << 5;        // wave-uniform dest base (elems)

  // fragment read offsets (swizzled column), ELEMENT units
  int csw = ((fg ^ ((fr >> 1) & 3)) << 3);
  int offA[4], offB[2];
  #pragma unroll
  for (int mf = 0; mf < 4; ++mf)
    offA[mf] = (((mf << 4) + fr) << 5) + csw;
  #pragma unroll
  for (int nf = 0; nf < 2; ++nf)
    offB[nf] = (((wv << 5) + (nf << 4) + fr) << 5) + csw;

  auto stage = [&](int k, int bb) {
    int t  = k >> 3;
    int ky = (t >= 6) ? 2 : (t >= 3 ? 1 : 0);
    int kx = t - ky * 3;
    int ka = k << 5;
    int kb = ((ky * Wp + kx) << 8) + ((k & 7) << 5);
    glds16(gA0 + ka, &Asm[bb][dW]);
    glds16(gB[0] + kb, &Bsm[bb][dW]);
    glds16(gB[1] + kb, &Bsm[bb][2048 + dW]);
  };

  f32x4 acc[4][2] = {};

  stage(0, 0);
  #pragma unroll 1
  for (int k = 0; k < 72; ++k) {
    int cur = k & 1;
    __syncthreads();
    if (k < 71) stage(k + 1, cur ^ 1);
    bfrag af[4], bfv[2];
    #pragma unroll
    for (int mf = 0; mf < 4; ++mf)
      if (mf < nmf) af[mf] = *(const bfrag*)&Asm[cur][offA[mf]];
    #pragma unroll
    for (int nf = 0; nf < 2; ++nf)
      bfv[nf] = *(const bfrag*)&Bsm[cur][offB[nf]];
    #pragma unroll
    for (int mf = 0; mf < 4; ++mf)
      if (mf < nmf)
        #pragma unroll
        for (int nf = 0; nf < 2; ++nf)
          acc[mf][nf] = __builtin_amdgcn_mfma_f32_16x16x32_bf16(
              af[mf], bfv[nf], acc[mf][nf], 0, 0, 0);
  }

  // scatter epilogue
  #pragma unroll
  for (int nf = 0; nf < 2; ++nf) {
    int pp = p0 + (wv << 5) + (nf << 4) + fr;
    if (pp >= L.P) continue;
    int n2 = pp >> L.logHW;
    int y2 = (pp >> L.logW) & (L.H - 1);
    int x2 = pp & (L.W - 1);
    int sp_off = L.aoff + y2 * L.W + x2;
    #pragma unroll
    for (int mf = 0; mf < 4; ++mf) {
      if (mf < nmf) {
        #pragma unroll
        for (int j = 0; j < 4; ++j) {
          int co = (mf << 4) + (fg << 2) + j;
          if (co < Cout) {
            float val = acc[mf][nf][j] + biasO[co];
            int g   = co / 6;
            int box = co - g * 6;
            size_t idx;
            if (isCls) idx = (size_t)CLS_BASE + ((size_t)n2 * 9 + g) * TOTAL_ANCH
                             + sp_off + box * L.HW;
            else       idx = ((size_t)n2 * 4 + g) * TOTAL_ANCH + sp_off + box * L.HW;
            dout[idx] = val;
          }
        }
      }
    }
  }
}

extern "C" void kernel_launch(void* const* d_in, const int* in_sizes, int n_in,
                              void* d_out, int out_size, void* d_ws, size_t ws_size,
                              hipStream_t stream) {
  if (ws_size < WS_ELEMS * 2) return;  // fail loud: output stays poisoned

  static const int kH[6]      = {32, 16, 8, 4, 2, 1};
  static const int kW[6]      = {256, 128, 64, 32, 16, 8};
  static const int kLogW[6]   = {8, 7, 6, 5, 4, 3};
  static const int kLogHW[6]  = {13, 11, 9, 7, 5, 3};
  static const int kActOff[6] = {0, 17965056, 22757376, 24109056, 24526848, 24674304};
  static const int kAoff[6]   = {0, 49152, 61440, 64512, 65280, 65472};
  static const int kBlkMid[6] = {0, 1024, 1280, 1344, 1360, 1364};
  static const int kBlkOut[6] = {0, 512, 640, 672, 680, 682};
  static const int kPosSt[6]  = {0, 65536, 81920, 86016, 87040, 87296};

  FPtrs fp;
  for (int i = 0; i < 6; ++i) fp.f[i] = (const float*)d_in[i];
  const float* reg_w  = (const float*)d_in[6];
  const float* reg_b  = (const float*)d_in[7];
  const float* reg_wo = (const float*)d_in[8];
  const float* reg_bo = (const float*)d_in[9];
  const float* cls_w  = (const float*)d_in[10];
  const float* cls_b  = (const float*)d_in[11];
  const float* cls_wo = (const float*)d_in[12];
  const float* cls_bo = (const float*)d_in[13];
  __bf16* ws = (__bf16*)d_ws;

  Desc dmid, dout_d;
  for (int i = 0; i < 6; ++i) {
    LevelD L;
    L.H = kH[i]; L.W = kW[i]; L.logW = kLogW[i]; L.logHW = kLogHW[i];
    L.HW = kH[i] * kW[i]; L.P = 8 * L.HW;
    L.act_off = kActOff[i]; L.aoff = kAoff[i];
    L.pos_start = kPosSt[i];
    L.blk_start = kBlkMid[i];
    dmid.lv[i] = L;
    L.blk_start = kBlkOut[i];
    dout_d.lv[i] = L;
  }

  // zero both activation buffers (halos must be zero)
  hipMemsetAsync((char*)d_ws + (size_t)ACT0_OFF * 2, 0,
                 (size_t)ACT_ELEMS * 2 * 2, stream);

  prep_k<<<256, 256, 0, stream>>>(reg_w,  ws + WREG_OFF,  1024 * 2304);
  prep_k<<<256, 256, 0, stream>>>(cls_w,  ws + WCLS_OFF,  1024 * 2304);
  prep_k<<<64,  256, 0, stream>>>(reg_wo, ws + WREGO_OFF, 24 * 2304);
  prep_k<<<64,  256, 0, stream>>>(cls_wo, ws + WCLSO_OFF, 54 * 2304);

  for (int head = 0; head < 2; ++head) {
    convert_k<<<5460, 256, 0, stream>>>(fp, ws + ACT0_OFF, dmid);
    const __bf16* wT = ws + (head ? WCLS_OFF : WREG_OFF);
    const float*  bb = head ? cls_b : reg_b;
    conv_mid_k<<<1366, 256, 0, stream>>>(ws + ACT0_OFF, ws + ACT1_OFF, wT + 0 * 589824, bb + 0,   dmid);
    conv_mid_k<<<1366, 256, 0, stream>>>(ws + ACT1_OFF, ws + ACT0_OFF, wT + 1 * 589824, bb + 256, dmid);
    conv_mid_k<<<1366, 256, 0, stream>>>(ws + ACT0_OFF, ws + ACT1_OFF, wT + 2 * 589824, bb + 512, dmid);
    conv_mid_k<<<1366, 256, 0, stream>>>(ws + ACT1_OFF, ws + ACT0_OFF, wT + 3 * 589824, bb + 768, dmid);
    conv_out_k<<<683, 256, 0, stream>>>(ws + ACT0_OFF,
        ws + (head ? WCLSO_OFF : WREGO_OFF), head ? cls_bo : reg_bo,
        (float*)d_out, dout_d, head ? 54 : 24, head);
  }
}

// Round 8
// 1317.363 us; speedup vs baseline: 1.2279x; 1.0910x over previous
//
#include <hip/hip_runtime.h>
#include <hip/hip_bf16.h>

// RetinaNet head on MI355X. R8 = R7 + bijective XCD-chunked block swizzle
// (T1/m204) on both conv kernels: mt-pairs and halo-neighbor tiles now share
// one XCD's L2, attacking the measured 9.4x over-fetch (349MB vs 37MB unique).

typedef float  f32x4 __attribute__((ext_vector_type(4)));
typedef int    i32x4 __attribute__((ext_vector_type(4)));
typedef __bf16 bfrag __attribute__((ext_vector_type(8)));
typedef __bf16 bf4   __attribute__((ext_vector_type(4)));

struct LevelD {
  int H, W, logW, logHW, P, HW, act_off, aoff, blk_start, pos_start;
};
struct Desc  { LevelD lv[6]; };
struct FPtrs { const float* f[6]; };

#define ACT_ELEMS  24735744
#define WREG_OFF   0
#define WCLS_OFF   2359296
#define WREGO_OFF  4718592
#define WCLSO_OFF  4773888
#define ACT0_OFF   4898304
#define ACT1_OFF   29634048
#define WS_ELEMS   54369792ull
#define TOTAL_ANCH 65520
#define CLS_BASE   2096640

__device__ __forceinline__ void glds16(const __bf16* g, __bf16* l) {
  __builtin_amdgcn_global_load_lds(
      (const __attribute__((address_space(1))) void*)g,
      (__attribute__((address_space(3))) void*)l, 16, 0, 0);
}

// bijective XCD-chunk swizzle (m204): blocks with equal (blockIdx%8) — which
// dispatch to the same XCD — get a CONTIGUOUS range of work ids.
__device__ __forceinline__ int xcd_swz(int b, int nwg) {
  int xcd = b & 7;
  int q = nwg >> 3, r = nwg & 7;
  int base = (xcd < r) ? xcd * (q + 1) : r * (q + 1) + (xcd - r) * q;
  return base + (b >> 3);
}

// ---- weight prep: [CO][256ci][3][3] f32 -> [CO][t=9][256ci] bf16 ----
__global__ __launch_bounds__(256) void prep_k(const float* __restrict__ w,
                                              __bf16* __restrict__ o, int total)
{
  for (int i = blockIdx.x * 256 + threadIdx.x; i < total; i += gridDim.x * 256) {
    int co = i / 2304;
    int r  = i - co * 2304;
    int t  = r >> 8;
    int ci = r & 255;
    o[i] = (__bf16)w[((co << 8) + ci) * 9 + t];
  }
}

// ---- NCHW f32 feat -> padded NHWC bf16 (interior only; halos pre-zeroed) ----
__global__ __launch_bounds__(256) void convert_k(FPtrs fp, __bf16* __restrict__ act, Desc d)
{
  __shared__ __bf16 T[16 * 264];
  int b  = blockIdx.x;
  int p0 = b << 4;
  int li = 0;
  #pragma unroll
  for (int i = 1; i < 6; ++i) li = (p0 >= d.lv[i].pos_start) ? i : li;
  LevelD L = d.lv[li];
  int lp  = b * 16 - L.pos_start;
  int tid = threadIdx.x;
  int pl = tid & 15;
  int p  = lp + pl;
  int n  = p >> L.logHW;
  int y  = (p >> L.logW) & (L.H - 1);
  int x  = p & (L.W - 1);
  const float* src = fp.f[li];
  size_t base = (size_t)n * ((size_t)L.HW << 8) + (size_t)y * L.W + x;
  int c0 = tid >> 4;
  #pragma unroll
  for (int it = 0; it < 16; ++it) {
    int c = c0 + (it << 4);
    T[pl * 264 + c] = (__bf16)src[base + (size_t)c * L.HW];
  }
  __syncthreads();
  int p2 = tid >> 4;
  int cc = (tid & 15) << 4;
  int pg = lp + p2;
  int n2 = pg >> L.logHW;
  int y2 = (pg >> L.logW) & (L.H - 1);
  int x2 = pg & (L.W - 1);
  __bf16* dst = act + L.act_off +
      ((size_t)((n2 * (L.H + 2) + y2 + 1) * (L.W + 2) + x2 + 1) << 8) + cc;
  i32x4 v0 = *(const i32x4*)&T[p2 * 264 + cc];
  i32x4 v1 = *(const i32x4*)&T[p2 * 264 + cc + 8];
  *(i32x4*)dst       = v0;
  *(i32x4*)(dst + 8) = v1;
}

// ---- mid conv: 256->256, +bias, ReLU ----
// 128x128 tile, BK=32, 4 waves (2x2), dbuf LDS, 1 barrier/K-step.
__global__ __launch_bounds__(256, 3)
void conv_mid_k(const __bf16* __restrict__ inb, __bf16* __restrict__ outb,
                const __bf16* __restrict__ wT, const float* __restrict__ bias,
                Desc d)
{
  __shared__ __bf16 Al[2][128 * 32];   // linear [co][ci32], 64B rows
  __shared__ __bf16 Bl[2][128 * 32];   // linear [pos][ci32]
  int b  = xcd_swz(blockIdx.x, 1366);
  int li = 0;
  #pragma unroll
  for (int i = 1; i < 6; ++i) li = (b >= d.lv[i].blk_start) ? i : li;
  LevelD L  = d.lv[li];
  int local = b - L.blk_start;
  int mt = local & 1;
  int nt = local >> 1;
  int m0 = mt << 7;
  int p0 = nt << 7;
  int tid  = threadIdx.x;
  int lane = tid & 63;
  int wv   = tid >> 6;
  int wm = wv >> 1, wn = wv & 1;
  int fr = lane & 15, fg = lane >> 4;
  int Wp = L.W + 2;

  // staging decode: wave wv covers rows wv*16 + r*64 (r=0,1), lane -> (rsub, slot)
  int rsub = lane >> 2;
  int slot = lane & 3;
  int sw   = slot ^ ((rsub >> 1) & 3);          // XOR slot-swizzle (source side)

  const __bf16* gA[2];
  const __bf16* gB[2];
  int ldsA[2];
  #pragma unroll
  for (int r = 0; r < 2; ++r) {
    int row = (r << 6) + (wv << 4) + rsub;
    gA[r] = wT + (m0 + row) * 2304 + (sw << 3);
    int p  = p0 + row;
    int pc = (p < L.P) ? p : 0;
    int n  = pc >> L.logHW;
    int y  = (pc >> L.logW) & (L.H - 1);
    int x  = pc & (L.W - 1);
    gB[r] = inb + L.act_off + (((n * (L.H + 2) + y) * Wp + x) << 8) + (sw << 3);
    ldsA[r] = ((r << 6) + (wv << 4)) << 5;      // row*32 elems, wave base
  }

  // fragment read offsets (swizzled column), ELEMENT units
  int csw = ((fg ^ ((fr >> 1) & 3)) << 3);
  int offA[4], offB[4];
  #pragma unroll
  for (int f = 0; f < 4; ++f) {
    offA[f] = (((wm << 6) + (f << 4) + fr) << 5) + csw;
    offB[f] = (((wn << 6) + (f << 4) + fr) << 5) + csw;
  }

  auto stage = [&](int k, int bb) {
    int t  = k >> 3;
    int c0 = (k & 7) << 5;
    int ky = (t >= 6) ? 2 : (t >= 3 ? 1 : 0);
    int kx = t - ky * 3;
    int koffA = (t << 8) + c0;
    int koffB = ((ky * Wp + kx) << 8) + c0;
    glds16(gA[0] + koffA, &Al[bb][ldsA[0]]);
    glds16(gA[1] + koffA, &Al[bb][ldsA[1]]);
    glds16(gB[0] + koffB, &Bl[bb][ldsA[0]]);
    glds16(gB[1] + koffB, &Bl[bb][ldsA[1]]);
  };

  f32x4 acc[4][4] = {};

  stage(0, 0);
  #pragma unroll 1
  for (int k = 0; k < 72; ++k) {
    int cur = k & 1;
    __syncthreads();                 // stage(k) landed (flew during compute(k-1))
    if (k < 71) stage(k + 1, cur ^ 1);
    bfrag af[4], bfv[4];
    #pragma unroll
    for (int mf = 0; mf < 4; ++mf) af[mf]  = *(const bfrag*)&Al[cur][offA[mf]];
    #pragma unroll
    for (int nf = 0; nf < 4; ++nf) bfv[nf] = *(const bfrag*)&Bl[cur][offB[nf]];
    #pragma unroll
    for (int mf = 0; mf < 4; ++mf)
      #pragma unroll
      for (int nf = 0; nf < 4; ++nf)
        acc[mf][nf] = __builtin_amdgcn_mfma_f32_16x16x32_bf16(af[mf], bfv[nf],
                                                              acc[mf][nf], 0, 0, 0);
  }

  // epilogue: bias + relu -> bf16 NHWC interior
  #pragma unroll
  for (int nf = 0; nf < 4; ++nf) {
    int pp = p0 + (wn << 6) + (nf << 4) + fr;
    if (pp >= L.P) continue;
    int n2 = pp >> L.logHW;
    int y2 = (pp >> L.logW) & (L.H - 1);
    int x2 = pp & (L.W - 1);
    __bf16* ob = outb + L.act_off + (((n2 * (L.H + 2) + y2 + 1) * Wp + x2 + 1) << 8);
    #pragma unroll
    for (int mf = 0; mf < 4; ++mf) {
      int cob = m0 + (wm << 6) + (mf << 4) + (fg << 2);
      f32x4 bb = *(const f32x4*)(bias + cob);
      f32x4 v  = acc[mf][nf];
      bf4 ov;
      #pragma unroll
      for (int j = 0; j < 4; ++j) ov[j] = (__bf16)fmaxf(v[j] + bb[j], 0.0f);
      *(bf4*)(ob + cob) = ov;
    }
  }
}

// ---- out conv: 256->Cout (24 reg / 54 cls), +bias, scatter f32 to d_out ----
// BM=Cout (<=64), BN=128; 4 waves = pos quarters, wave tile Cout x 32.
__global__ __launch_bounds__(256, 3)
void conv_out_k(const __bf16* __restrict__ inb, const __bf16* __restrict__ wT,
                const float* __restrict__ biasO, float* __restrict__ dout,
                Desc d, int Cout, int isCls)
{
  __shared__ __bf16 Asm[2][64 * 32];
  __shared__ __bf16 Bsm[2][128 * 32];
  int b  = xcd_swz(blockIdx.x, 683);
  int li = 0;
  #pragma unroll
  for (int i = 1; i < 6; ++i) li = (b >= d.lv[i].blk_start) ? i : li;
  LevelD L = d.lv[li];
  int p0 = (b - L.blk_start) << 7;
  int tid  = threadIdx.x;
  int lane = tid & 63;
  int wv   = tid >> 6;            // wave = pos quarter
  int fr = lane & 15, fg = lane >> 4;
  int Wp = L.W + 2;
  int nmf = (Cout + 15) >> 4;     // 2 (reg) or 4 (cls)

  int rsub = lane >> 2;
  int slot = lane & 3;
  int sw   = slot ^ ((rsub >> 1) & 3);

  const __bf16* gA0;
  {
    int row = (wv << 4) + rsub;               // 0..63
    int co  = (row < Cout) ? row : 0;
    gA0 = wT + co * 2304 + (sw << 3);
  }
  const __bf16* gB[2];
  #pragma unroll
  for (int j = 0; j < 2; ++j) {
    int row = (j << 6) + (wv << 4) + rsub;
    int p  = p0 + row;
    int pc = (p < L.P) ? p : 0;
    int n = pc >> L.logHW, y = (pc >> L.logW) & (L.H - 1), x = pc & (L.W - 1);
    gB[j] = inb + L.act_off + (((n * (L.H + 2) + y) * Wp + x) << 8) + (sw << 3);
  }
  int dW = (wv << 4) << 5;        // wave-uniform dest base (elems)

  // fragment read offsets (swizzled column), ELEMENT units
  int csw = ((fg ^ ((fr >> 1) & 3)) << 3);
  int offA[4], offB[2];
  #pragma unroll
  for (int mf = 0; mf < 4; ++mf)
    offA[mf] = (((mf << 4) + fr) << 5) + csw;
  #pragma unroll
  for (int nf = 0; nf < 2; ++nf)
    offB[nf] = (((wv << 5) + (nf << 4) + fr) << 5) + csw;

  auto stage = [&](int k, int bb) {
    int t  = k >> 3;
    int ky = (t >= 6) ? 2 : (t >= 3 ? 1 : 0);
    int kx = t - ky * 3;
    int ka = k << 5;
    int kb = ((ky * Wp + kx) << 8) + ((k & 7) << 5);
    glds16(gA0 + ka, &Asm[bb][dW]);
    glds16(gB[0] + kb, &Bsm[bb][dW]);
    glds16(gB[1] + kb, &Bsm[bb][2048 + dW]);
  };

  f32x4 acc[4][2] = {};

  stage(0, 0);
  #pragma unroll 1
  for (int k = 0; k < 72; ++k) {
    int cur = k & 1;
    __syncthreads();
    if (k < 71) stage(k + 1, cur ^ 1);
    bfrag af[4], bfv[2];
    #pragma unroll
    for (int mf = 0; mf < 4; ++mf)
      if (mf < nmf) af[mf] = *(const bfrag*)&Asm[cur][offA[mf]];
    #pragma unroll
    for (int nf = 0; nf < 2; ++nf)
      bfv[nf] = *(const bfrag*)&Bsm[cur][offB[nf]];
    #pragma unroll
    for (int mf = 0; mf < 4; ++mf)
      if (mf < nmf)
        #pragma unroll
        for (int nf = 0; nf < 2; ++nf)
          acc[mf][nf] = __builtin_amdgcn_mfma_f32_16x16x32_bf16(
              af[mf], bfv[nf], acc[mf][nf], 0, 0, 0);
  }

  // scatter epilogue
  #pragma unroll
  for (int nf = 0; nf < 2; ++nf) {
    int pp = p0 + (wv << 5) + (nf << 4) + fr;
    if (pp >= L.P) continue;
    int n2 = pp >> L.logHW;
    int y2 = (pp >> L.logW) & (L.H - 1);
    int x2 = pp & (L.W - 1);
    int sp_off = L.aoff + y2 * L.W + x2;
    #pragma unroll
    for (int mf = 0; mf < 4; ++mf) {
      if (mf < nmf) {
        #pragma unroll
        for (int j = 0; j < 4; ++j) {
          int co = (mf << 4) + (fg << 2) + j;
          if (co < Cout) {
            float val = acc[mf][nf][j] + biasO[co];
            int g   = co / 6;
            int box = co - g * 6;
            size_t idx;
            if (isCls) idx = (size_t)CLS_BASE + ((size_t)n2 * 9 + g) * TOTAL_ANCH
                             + sp_off + box * L.HW;
            else       idx = ((size_t)n2 * 4 + g) * TOTAL_ANCH + sp_off + box * L.HW;
            dout[idx] = val;
          }
        }
      }
    }
  }
}

extern "C" void kernel_launch(void* const* d_in, const int* in_sizes, int n_in,
                              void* d_out, int out_size, void* d_ws, size_t ws_size,
                              hipStream_t stream) {
  if (ws_size < WS_ELEMS * 2) return;  // fail loud: output stays poisoned

  static const int kH[6]      = {32, 16, 8, 4, 2, 1};
  static const int kW[6]      = {256, 128, 64, 32, 16, 8};
  static const int kLogW[6]   = {8, 7, 6, 5, 4, 3};
  static const int kLogHW[6]  = {13, 11, 9, 7, 5, 3};
  static const int kActOff[6] = {0, 17965056, 22757376, 24109056, 24526848, 24674304};
  static const int kAoff[6]   = {0, 49152, 61440, 64512, 65280, 65472};
  static const int kBlkMid[6] = {0, 1024, 1280, 1344, 1360, 1364};
  static const int kBlkOut[6] = {0, 512, 640, 672, 680, 682};
  static const int kPosSt[6]  = {0, 65536, 81920, 86016, 87040, 87296};

  FPtrs fp;
  for (int i = 0; i < 6; ++i) fp.f[i] = (const float*)d_in[i];
  const float* reg_w  = (const float*)d_in[6];
  const float* reg_b  = (const float*)d_in[7];
  const float* reg_wo = (const float*)d_in[8];
  const float* reg_bo = (const float*)d_in[9];
  const float* cls_w  = (const float*)d_in[10];
  const float* cls_b  = (const float*)d_in[11];
  const float* cls_wo = (const float*)d_in[12];
  const float* cls_bo = (const float*)d_in[13];
  __bf16* ws = (__bf16*)d_ws;

  Desc dmid, dout_d;
  for (int i = 0; i < 6; ++i) {
    LevelD L;
    L.H = kH[i]; L.W = kW[i]; L.logW = kLogW[i]; L.logHW = kLogHW[i];
    L.HW = kH[i] * kW[i]; L.P = 8 * L.HW;
    L.act_off = kActOff[i]; L.aoff = kAoff[i];
    L.pos_start = kPosSt[i];
    L.blk_start = kBlkMid[i];
    dmid.lv[i] = L;
    L.blk_start = kBlkOut[i];
    dout_d.lv[i] = L;
  }

  // zero both activation buffers (halos must be zero)
  hipMemsetAsync((char*)d_ws + (size_t)ACT0_OFF * 2, 0,
                 (size_t)ACT_ELEMS * 2 * 2, stream);

  prep_k<<<256, 256, 0, stream>>>(reg_w,  ws + WREG_OFF,  1024 * 2304);
  prep_k<<<256, 256, 0, stream>>>(cls_w,  ws + WCLS_OFF,  1024 * 2304);
  prep_k<<<64,  256, 0, stream>>>(reg_wo, ws + WREGO_OFF, 24 * 2304);
  prep_k<<<64,  256, 0, stream>>>(cls_wo, ws + WCLSO_OFF, 54 * 2304);

  for (int head = 0; head < 2; ++head) {
    convert_k<<<5460, 256, 0, stream>>>(fp, ws + ACT0_OFF, dmid);
    const __bf16* wT = ws + (head ? WCLS_OFF : WREG_OFF);
    const float*  bb = head ? cls_b : reg_b;
    conv_mid_k<<<1366, 256, 0, stream>>>(ws + ACT0_OFF, ws + ACT1_OFF, wT + 0 * 589824, bb + 0,   dmid);
    conv_mid_k<<<1366, 256, 0, stream>>>(ws + ACT1_OFF, ws + ACT0_OFF, wT + 1 * 589824, bb + 256, dmid);
    conv_mid_k<<<1366, 256, 0, stream>>>(ws + ACT0_OFF, ws + ACT1_OFF, wT + 2 * 589824, bb + 512, dmid);
    conv_mid_k<<<1366, 256, 0, stream>>>(ws + ACT1_OFF, ws + ACT0_OFF, wT + 3 * 589824, bb + 768, dmid);
    conv_out_k<<<683, 256, 0, stream>>>(ws + ACT0_OFF,
        ws + (head ? WCLSO_OFF : WREGO_OFF), head ? cls_bo : reg_bo,
        (float*)d_out, dout_d, head ? 54 : 24, head);
  }
}